// Round 1
// baseline (806.741 us; speedup 1.0000x reference)
//
#include <hip/hip_runtime.h>
#include <math.h>

// Problem constants (from reference)
#define BB     64
#define SS     8192
#define DD     64
#define NBINS  256
#define TPB    1024   // 16 waves per block

// One block per batch. LDS holds per-batch bin sums (256*64 fp32 = 64 KiB)
// and counts (1 KiB). Each wave processes one token at a time: lane = D index,
// so ds_add_f32 addresses are bin*64+lane -> 2-way bank aliasing (free).
__global__ __launch_bounds__(TPB) void embedder_kernel(
    const float* __restrict__ T,
    const int*   __restrict__ X_ids,
    const float* __restrict__ embedX,
    const float* __restrict__ embedW,
    float*       __restrict__ out)
{
    __shared__ float sums[NBINS * DD];   // 64 KiB
    __shared__ float counts[NBINS];      // 1 KiB

    const int b   = blockIdx.x;
    const int tid = threadIdx.x;

    // Zero LDS accumulators
    for (int i = tid; i < NBINS * DD; i += TPB) sums[i] = 0.0f;
    for (int i = tid; i < NBINS; i += TPB)      counts[i] = 0.0f;
    __syncthreads();

    const int lane       = tid & 63;
    const int token_slot = tid >> 6;       // 0..15 (which wave)
    const int TOK_PAR    = TPB / 64;       // 16 tokens in flight per iteration

    const float* Tb = T     + (size_t)b * SS;
    const int*   Xb = X_ids + (size_t)b * SS;

    for (int s = token_slot; s < SS; s += TOK_PAR) {
        const float t  = Tb[s];      // wave-uniform load
        const int   id = Xb[s];      // wave-uniform load
        if (t < 256.0f) {
            const int bin = (int)t;  // floor for t in [0, 256)
            const float v = embedX[(size_t)id * DD + lane];  // coalesced 256B/token
            const float w = expf(embedW[id]);
            atomicAdd(&sums[bin * DD + lane], w * v);
            if (lane == 0) atomicAdd(&counts[bin], 1.0f);
        }
    }
    __syncthreads();

    // Epilogue: divide and write coalesced
    float* outb = out + (size_t)b * NBINS * DD;
    for (int i = tid; i < NBINS * DD; i += TPB) {
        const int bin = i >> 6;
        outb[i] = sums[i] / (counts[bin] + 1e-6f);
    }
}

extern "C" void kernel_launch(void* const* d_in, const int* in_sizes, int n_in,
                              void* d_out, int out_size, void* d_ws, size_t ws_size,
                              hipStream_t stream) {
    const float* T      = (const float*)d_in[0];
    const int*   X_ids  = (const int*)  d_in[1];
    const float* embedX = (const float*)d_in[2];
    const float* embedW = (const float*)d_in[3];
    float* out = (float*)d_out;

    embedder_kernel<<<BB, TPB, 0, stream>>>(T, X_ids, embedX, embedW, out);
}

// Round 2
// 261.076 us; speedup vs baseline: 3.0901x; 3.0901x over previous
//
#include <hip/hip_runtime.h>
#include <math.h>

// Problem constants (from reference)
#define BB     64
#define SS     8192
#define DD     64
#define NBINS  256
#define TPB    1024   // 16 waves per block
#define SPLIT  8      // blocks per batch -> 512 blocks total, 2/CU (LDS-limited)

// Tokens per block = SS/SPLIT = 1024; each of the 16 waves owns exactly one
// 64-token chunk: lanes load (T,id) coalesced, gather embedW + expf once per
// token in parallel, then a 64-iter inner loop broadcasts bin/id/w to SGPRs
// via readlane so the embedX gather is scalar-base + lane*4 (256 B/wave).
__global__ __launch_bounds__(TPB) void accum_kernel(
    const float* __restrict__ T,
    const int*   __restrict__ X_ids,
    const float* __restrict__ embedX,
    const float* __restrict__ embedW,
    float*       __restrict__ out_sums,   // [BB][NBINS][DD], pre-zeroed
    float*       __restrict__ ws_counts)  // [BB][NBINS], pre-zeroed
{
    __shared__ float sums[NBINS * DD];   // 64 KiB
    __shared__ float counts[NBINS];      // 1 KiB

    const int blk  = blockIdx.x;
    const int b    = blk / SPLIT;
    const int part = blk % SPLIT;
    const int tid  = threadIdx.x;
    const int lane = tid & 63;
    const int wave = tid >> 6;           // 0..15

    for (int i = tid; i < NBINS * DD; i += TPB) sums[i] = 0.0f;
    if (tid < NBINS) counts[tid] = 0.0f;
    __syncthreads();

    // This wave's 64-token chunk
    const int s0 = part * (SS / SPLIT) + wave * 64;
    const float t  = T[(size_t)b * SS + s0 + lane];
    const int   id = X_ids[(size_t)b * SS + s0 + lane];
    const float w  = expf(embedW[id]);               // parallel 4B gather + exp
    const int   bin = (t < 256.0f) ? (int)t : -1;    // -1 = dummy bin (skip)

    // per-lane count contribution (one LDS atomic per token)
    if (bin >= 0) atomicAdd(&counts[bin], 1.0f);

    const int w_bits = __float_as_int(w);

    #pragma unroll 4
    for (int j = 0; j < 64; ++j) {
        const int s_bin = __builtin_amdgcn_readlane(bin, j);     // SGPR
        if (s_bin >= 0) {
            const int   s_id = __builtin_amdgcn_readlane(id, j);
            const float s_w  = __int_as_float(__builtin_amdgcn_readlane(w_bits, j));
            const float v = embedX[(size_t)s_id * DD + lane];    // coalesced 256B
            atomicAdd(&sums[s_bin * DD + lane], s_w * v);        // 2-way banks: free
        }
    }
    __syncthreads();

    // Merge partials into global accumulators
    float* gs = out_sums + (size_t)b * NBINS * DD;
    for (int i = tid; i < NBINS * DD; i += TPB)
        atomicAdd(&gs[i], sums[i]);
    if (tid < NBINS)
        atomicAdd(&ws_counts[b * NBINS + tid], counts[tid]);
}

__global__ __launch_bounds__(256) void finalize_kernel(
    float* __restrict__ out,              // sums in, result out (in-place)
    const float* __restrict__ ws_counts)
{
    const int i = blockIdx.x * 256 + threadIdx.x;   // 0 .. BB*NBINS*DD-1
    const int bin_global = i >> 6;                  // b*NBINS + bin
    out[i] = out[i] / (ws_counts[bin_global] + 1e-6f);
}

extern "C" void kernel_launch(void* const* d_in, const int* in_sizes, int n_in,
                              void* d_out, int out_size, void* d_ws, size_t ws_size,
                              hipStream_t stream) {
    const float* T      = (const float*)d_in[0];
    const int*   X_ids  = (const int*)  d_in[1];
    const float* embedX = (const float*)d_in[2];
    const float* embedW = (const float*)d_in[3];
    float* out       = (float*)d_out;
    float* ws_counts = (float*)d_ws;     // BB*NBINS floats = 64 KiB

    hipMemsetAsync(out, 0, (size_t)BB * NBINS * DD * sizeof(float), stream);
    hipMemsetAsync(ws_counts, 0, (size_t)BB * NBINS * sizeof(float), stream);

    accum_kernel<<<BB * SPLIT, TPB, 0, stream>>>(T, X_ids, embedX, embedW,
                                                 out, ws_counts);
    finalize_kernel<<<(BB * NBINS * DD) / 256, 256, 0, stream>>>(out, ws_counts);
}

// Round 3
// 253.230 us; speedup vs baseline: 3.1858x; 1.0310x over previous
//
#include <hip/hip_runtime.h>
#include <math.h>

// Problem constants (from reference)
#define BB     64
#define SS     8192
#define DD     64
#define NBINS  256
#define TPB    1024   // 16 waves per block
#define SPLIT  8      // blocks per batch -> 512 blocks, 2/CU (LDS-limited)
#define NPART  (BB * SPLIT)
#define PART_ELEMS (NBINS * DD)          // 16384 per-partial sum elements

// ws layout (path A): [NPART][NBINS*DD] partial sums, then [NPART][NBINS] counts
#define WS_SUMS_ELEMS   ((size_t)NPART * PART_ELEMS)
#define WS_COUNTS_ELEMS ((size_t)NPART * NBINS)
#define WS_NEEDED ((WS_SUMS_ELEMS + WS_COUNTS_ELEMS) * sizeof(float))

// -------- Path A: partials to ws (plain stores), reduce kernel merges --------
__global__ __launch_bounds__(TPB) void accum_part_kernel(
    const float* __restrict__ T,
    const int*   __restrict__ X_ids,
    const float* __restrict__ embedX,
    const float* __restrict__ embedW,
    float*       __restrict__ ws_sums,    // [NPART][NBINS*DD]
    float*       __restrict__ ws_counts)  // [NPART][NBINS]
{
    __shared__ float sums[(NBINS + 1) * DD];   // +1 dummy bin row
    __shared__ float counts[NBINS + 1];

    const int blk  = blockIdx.x;
    const int b    = blk / SPLIT;
    const int part = blk % SPLIT;
    const int tid  = threadIdx.x;
    const int lane = tid & 63;
    const int wave = tid >> 6;

    for (int i = tid; i < (NBINS + 1) * DD; i += TPB) sums[i] = 0.0f;
    if (tid < NBINS + 1) counts[tid] = 0.0f;
    __syncthreads();

    // This wave's 64-token chunk (coalesced lane-parallel loads)
    const int s0 = part * (SS / SPLIT) + wave * 64;
    const float t  = T[(size_t)b * SS + s0 + lane];
    const int   id = X_ids[(size_t)b * SS + s0 + lane];
    const float w  = expf(embedW[id]);
    const int   bin = (t < 256.0f) ? (int)t : NBINS;   // NBINS = dummy bin

    atomicAdd(&counts[bin], 1.0f);

    const int w_bits = __float_as_int(w);

    // Branchless, grouped: 8 independent gathers in flight per wave
    #pragma unroll
    for (int j = 0; j < 64; j += 8) {
        float v[8], sw[8];
        int   sb[8];
        #pragma unroll
        for (int u = 0; u < 8; ++u) {
            const int s_id = __builtin_amdgcn_readlane(id, j + u);
            sb[u] = __builtin_amdgcn_readlane(bin, j + u);
            sw[u] = __int_as_float(__builtin_amdgcn_readlane(w_bits, j + u));
            v[u]  = embedX[(size_t)s_id * DD + lane];   // coalesced 256B/wave
        }
        #pragma unroll
        for (int u = 0; u < 8; ++u)
            atomicAdd(&sums[sb[u] * DD + lane], sw[u] * v[u]);  // 2-way banks: free
    }
    __syncthreads();

    // Plain coalesced stores of this block's partials (no zeroing needed: full write)
    float* gs = ws_sums + (size_t)blk * PART_ELEMS;
    for (int i = tid; i < PART_ELEMS; i += TPB) gs[i] = sums[i];
    if (tid < NBINS) ws_counts[(size_t)blk * NBINS + tid] = counts[tid];
}

__global__ __launch_bounds__(256) void reduce_kernel(
    const float* __restrict__ ws_sums,
    const float* __restrict__ ws_counts,
    float*       __restrict__ out)
{
    const int i = blockIdx.x * 256 + threadIdx.x;   // 0 .. BB*NBINS*DD-1
    const int r = i & (PART_ELEMS - 1);             // bin*64 + d
    const int b = i >> 14;                          // /16384
    const int bin = r >> 6;

    float s = 0.0f, c = 0.0f;
    #pragma unroll
    for (int p = 0; p < SPLIT; ++p) {
        const int blk = b * SPLIT + p;
        s += ws_sums[(size_t)blk * PART_ELEMS + r];
        c += ws_counts[(size_t)blk * NBINS + bin];
    }
    out[i] = s / (c + 1e-6f);
}

// -------- Path B fallback: global-atomic merge (small ws) --------
__global__ __launch_bounds__(TPB) void accum_atomic_kernel(
    const float* __restrict__ T,
    const int*   __restrict__ X_ids,
    const float* __restrict__ embedX,
    const float* __restrict__ embedW,
    float*       __restrict__ out_sums,
    float*       __restrict__ ws_counts)
{
    __shared__ float sums[(NBINS + 1) * DD];
    __shared__ float counts[NBINS + 1];

    const int blk  = blockIdx.x;
    const int b    = blk / SPLIT;
    const int part = blk % SPLIT;
    const int tid  = threadIdx.x;
    const int lane = tid & 63;
    const int wave = tid >> 6;

    for (int i = tid; i < (NBINS + 1) * DD; i += TPB) sums[i] = 0.0f;
    if (tid < NBINS + 1) counts[tid] = 0.0f;
    __syncthreads();

    const int s0 = part * (SS / SPLIT) + wave * 64;
    const float t  = T[(size_t)b * SS + s0 + lane];
    const int   id = X_ids[(size_t)b * SS + s0 + lane];
    const float w  = expf(embedW[id]);
    const int   bin = (t < 256.0f) ? (int)t : NBINS;

    atomicAdd(&counts[bin], 1.0f);
    const int w_bits = __float_as_int(w);

    #pragma unroll
    for (int j = 0; j < 64; j += 8) {
        float v[8], sw[8];
        int   sb[8];
        #pragma unroll
        for (int u = 0; u < 8; ++u) {
            const int s_id = __builtin_amdgcn_readlane(id, j + u);
            sb[u] = __builtin_amdgcn_readlane(bin, j + u);
            sw[u] = __int_as_float(__builtin_amdgcn_readlane(w_bits, j + u));
            v[u]  = embedX[(size_t)s_id * DD + lane];
        }
        #pragma unroll
        for (int u = 0; u < 8; ++u)
            atomicAdd(&sums[sb[u] * DD + lane], sw[u] * v[u]);
    }
    __syncthreads();

    float* gs = out_sums + (size_t)b * PART_ELEMS;
    for (int i = tid; i < PART_ELEMS; i += TPB) atomicAdd(&gs[i], sums[i]);
    if (tid < NBINS) atomicAdd(&ws_counts[b * NBINS + tid], counts[tid]);
}

__global__ __launch_bounds__(256) void finalize_kernel(
    float* __restrict__ out,
    const float* __restrict__ ws_counts)
{
    const int i = blockIdx.x * 256 + threadIdx.x;
    out[i] = out[i] / (ws_counts[i >> 6] + 1e-6f);
}

extern "C" void kernel_launch(void* const* d_in, const int* in_sizes, int n_in,
                              void* d_out, int out_size, void* d_ws, size_t ws_size,
                              hipStream_t stream) {
    const float* T      = (const float*)d_in[0];
    const int*   X_ids  = (const int*)  d_in[1];
    const float* embedX = (const float*)d_in[2];
    const float* embedW = (const float*)d_in[3];
    float* out = (float*)d_out;

    if (ws_size >= WS_NEEDED) {
        float* ws_sums   = (float*)d_ws;
        float* ws_counts = ws_sums + WS_SUMS_ELEMS;
        accum_part_kernel<<<NPART, TPB, 0, stream>>>(T, X_ids, embedX, embedW,
                                                     ws_sums, ws_counts);
        reduce_kernel<<<(BB * NBINS * DD) / 256, 256, 0, stream>>>(
            ws_sums, ws_counts, out);
    } else {
        float* ws_counts = (float*)d_ws;   // BB*NBINS floats = 64 KiB
        hipMemsetAsync(out, 0, (size_t)BB * NBINS * DD * sizeof(float), stream);
        hipMemsetAsync(ws_counts, 0, (size_t)BB * NBINS * sizeof(float), stream);
        accum_atomic_kernel<<<NPART, TPB, 0, stream>>>(T, X_ids, embedX, embedW,
                                                       out, ws_counts);
        finalize_kernel<<<(BB * NBINS * DD) / 256, 256, 0, stream>>>(out, ws_counts);
    }
}